// Round 14
// baseline (46.641 us; speedup 1.0000x reference)
//
#include <hip/hip_runtime.h>
#include <math.h>

#define NC 17
#define PLANE 640000              // 200*200*16 voxels per batch
#define H2 (PLANE / 2)            // 320000 float2 per channel-plane
#define J 5                       // float2 slabs per thread
#define BPB 250                   // blocks per batch: 250*256*5 = 320000 float2
#define NBLK1 (2 * BPB)           // 500 blocks
#define SLOT 16                   // floats per accumulator slot (64 B line)
#define DONE_IDX (3 * NC * SLOT)  // u32 counter after the 51 slots
#define BETA_C 0.95f
#define ALPHA_C 5.0f
#define WPC_C 3.0f
#define IGNORE_C 255

// ---------------------------------------------------------------------------
// Wave64 sum on the VALU pipe via DPP (no DS-pipe bpermute).
// ---------------------------------------------------------------------------
#define DPP_ADD(v, ctrl)                                                        \
    do {                                                                        \
        int _t = __builtin_amdgcn_update_dpp(0, __float_as_int(v), (ctrl),      \
                                             0xf, 0xf, true);                   \
        (v) += __int_as_float(_t);                                              \
    } while (0)

__device__ __forceinline__ float wave_sum_dpp(float v) {
    DPP_ADD(v, 0x111);   // row_shr:1
    DPP_ADD(v, 0x112);   // row_shr:2
    DPP_ADD(v, 0x114);   // row_shr:4
    DPP_ADD(v, 0x118);   // row_shr:8
    DPP_ADD(v, 0x142);   // row_bcast:15
    DPP_ADD(v, 0x143);   // row_bcast:31
    return v;            // full wave sum in lane 63
}

__device__ __forceinline__ float bce_ones(float x) {
    // F.binary_cross_entropy(x, ones) = min(-log(max(x,1e-38)), 100)
    return fminf(-logf(fmaxf(x, 1e-38f)), 100.0f);
}

// acc layout: slot r (64 B apart) = kind*17+c; kind 0=nom, 1=sum_p, 2=cnt.
// done counter (u32) at float-index DONE_IDX. All zeroed by memset per call.

// ---------------------------------------------------------------------------
// Fused: softmax + per-class sums (R13 body) + atomic tail + last-block
// epilogue. NO threadfence anywhere: visibility via device-scope atomic RMW
// chain (acc atomics -> vmcnt(0) -> done RMW -> agent-scope atomic loads).
// ---------------------------------------------------------------------------
__global__ __launch_bounds__(256) void al_fused(const float* __restrict__ pred,
                                                const int* __restrict__ tgt,
                                                const float* __restrict__ f1_list,
                                                float* __restrict__ acc,
                                                unsigned* __restrict__ done,
                                                float* __restrict__ out) {
    const int bb  = blockIdx.x;
    const int b   = (bb >= BPB) ? 1 : 0;                       // block-uniform
    const int base = (bb - b * BPB) * (256 * J);               // first float2 of block
    const int tid = (int)threadIdx.x;
    const float2* p0 = reinterpret_cast<const float2*>(pred) + (size_t)(b * NC) * H2;
    const int2*   tg = reinterpret_cast<const int2*>(tgt) + (size_t)b * H2;

    __shared__ float lds[3 * NC];
    if (tid < 3 * NC) lds[tid] = 0.f;

    float sump[NC];
#pragma unroll
    for (int c = 0; c < NC; ++c) sump[c] = 0.f;

    float2 xA[NC], xB[NC];
    int2 tA, tB;

#define LOAD_SLAB(X, T, s)                                                      \
    do {                                                                        \
        const int n2 = base + (s) * 256 + tid;                                  \
        _Pragma("unroll")                                                       \
        for (int c = 0; c < NC; ++c) X[c] = p0[(size_t)c * H2 + n2];            \
        T = tg[n2];                                                             \
    } while (0)

#define COMP_SLAB(X, T)                                                         \
    do {                                                                        \
        float2 ss = make_float2(0.f, 0.f);                                      \
        _Pragma("unroll")                                                       \
        for (int c = 0; c < NC; ++c) {                                          \
            X[c].x = __expf(X[c].x); ss.x += X[c].x;                            \
            X[c].y = __expf(X[c].y); ss.y += X[c].y;                            \
        }                                                                       \
        const float j0 = (T.x != IGNORE_C) ? __builtin_amdgcn_rcpf(ss.x) : 0.f; \
        const float j1 = (T.y != IGNORE_C) ? __builtin_amdgcn_rcpf(ss.y) : 0.f; \
        float e0 = 0.f, e1 = 0.f;                                               \
        _Pragma("unroll")                                                       \
        for (int c = 0; c < NC; ++c) {                                          \
            sump[c] += X[c].x * j0 + X[c].y * j1;                               \
            e0 = (c == T.x) ? X[c].x : e0;                                      \
            e1 = (c == T.y) ? X[c].y : e1;                                      \
        }                                                                       \
        if (T.x != IGNORE_C) { atomicAdd(&lds[T.x], e0 * j0);                   \
                               atomicAdd(&lds[2 * NC + T.x], 1.0f); }           \
        if (T.y != IGNORE_C) { atomicAdd(&lds[T.y], e1 * j1);                   \
                               atomicAdd(&lds[2 * NC + T.y], 1.0f); }           \
    } while (0)

    LOAD_SLAB(xA, tA, 0);        // slab 0 in flight
    LOAD_SLAB(xB, tB, 1);        // slab 1 in flight
    __syncthreads();             // lds zero-init visible (loads already issued)

    COMP_SLAB(xA, tA);           // compute 0 while 1 returns
    LOAD_SLAB(xA, tA, 2);
    COMP_SLAB(xB, tB);           // compute 1 while 2 returns
    LOAD_SLAB(xB, tB, 3);
    COMP_SLAB(xA, tA);           // compute 2 while 3 returns
    LOAD_SLAB(xA, tA, 4);
    COMP_SLAB(xB, tB);           // compute 3 while 4 returns
    COMP_SLAB(xA, tA);           // compute 4

#undef LOAD_SLAB
#undef COMP_SLAB

    // single tail: 17 DPP chains; lane 63 of each wave -> LDS
#pragma unroll
    for (int c = 0; c < NC; ++c) sump[c] = wave_sum_dpp(sump[c]);
    if ((tid & 63) == 63) {
#pragma unroll
        for (int c = 0; c < NC; ++c) atomicAdd(&lds[NC + c], sump[c]);
    }
    __syncthreads();

    // 51 device-scope fp32 RMWs, each to its own 64-B line (wave 0 only)
    if (tid < 3 * NC) atomicAdd(&acc[tid * SLOT], lds[tid]);

    if (tid != 0) return;

    // my RMWs performed before I announce completion (same wave as the RMWs)
    asm volatile("s_waitcnt vmcnt(0)" ::: "memory");
    const unsigned old = atomicAdd(done, 1u);
    if (old != (unsigned)(NBLK1 - 1)) return;

    // ---- last block, thread 0: O(C) epilogue via agent-scope atomic loads ----
    float nom[NC], sump2[NC], cnt[NC];
    float n_mask = 0.f;
#pragma unroll
    for (int c = 0; c < NC; ++c) {
        nom[c]   = __hip_atomic_load(&acc[c * SLOT],            __ATOMIC_RELAXED, __HIP_MEMORY_SCOPE_AGENT);
        sump2[c] = __hip_atomic_load(&acc[(NC + c) * SLOT],     __ATOMIC_RELAXED, __HIP_MEMORY_SCOPE_AGENT);
        cnt[c]   = __hip_atomic_load(&acc[(2 * NC + c) * SLOT], __ATOMIC_RELAXED, __HIP_MEMORY_SCOPE_AGENT);
        n_mask += cnt[c];
    }

    float loss_list[NC], newf1[NC];
    float count = 0.f;
    for (int c = 0; c < NC; ++c) {
        const bool has = cnt[c] > 0.f;
        const float prec = (sump2[c] > 0.f) ? nom[c] / sump2[c] : 0.f;
        const float rec  = has ? nom[c] / cnt[c] : 0.f;
        const float negc = n_mask - cnt[c];
        const float spec_num = (n_mask - sump2[c]) - (cnt[c] - nom[c]);
        const float spec = (negc > 0.f) ? spec_num / negc : 0.f;

        float ll = 0.f;
        if (has) {
            ll  = (sump2[c] > 0.f) ? bce_ones(prec) : 0.f;
            ll += bce_ones(rec);
            ll += (negc > 0.f) ? bce_ones(spec) : 0.f;
        }
        loss_list[c] = ll;

        const float den = prec + rec;
        const float f1  = (den > 0.f) ? 2.f * prec * rec / den : 0.f;
        const float cur = has ? f1 : 0.f;
        newf1[c] = BETA_C * f1_list[c] + (1.f - BETA_C) * cur;
        count += has ? 1.f : 0.f;
    }

    const float wp = WPC_C * count;

    float mxl = -INFINITY;
    for (int c = 0; c < NC; ++c) {
        const float lg = (loss_list[c] != 0.f) ? ALPHA_C * (1.f - newf1[c]) : -INFINITY;
        mxl = fmaxf(mxl, lg);
    }
    float e[NC];
    float se = 0.f;
    for (int c = 0; c < NC; ++c) {
        const float lg = (loss_list[c] != 0.f) ? ALPHA_C * (1.f - newf1[c]) : -INFINITY;
        e[c] = expf(lg - mxl);    // exp(-inf) = 0 for unselected classes
        se += e[c];
    }

    float total = 0.f;
    for (int c = 0; c < NC; ++c) {
        const float sm = e[c] / se;
        total += loss_list[c] * (1.f + wp * sm);
    }
    out[0] = total / (count * (1.f + WPC_C));
}

// ---------------------------------------------------------------------------
extern "C" void kernel_launch(void* const* d_in, const int* in_sizes, int n_in,
                              void* d_out, int out_size, void* d_ws, size_t ws_size,
                              hipStream_t stream) {
    const float* pred    = (const float*)d_in[0];
    const int*   tgt     = (const int*)d_in[1];
    const float* f1_list = (const float*)d_in[2];
    float* out  = (float*)d_out;
    float* acc  = (float*)d_ws;                        // 51 padded slots
    unsigned* done = (unsigned*)d_ws + DONE_IDX;       // u32 after slots

    hipMemsetAsync(d_ws, 0, (DONE_IDX + 16) * sizeof(float), stream);
    al_fused<<<dim3(NBLK1), dim3(256), 0, stream>>>(pred, tgt, f1_list, acc, done, out);
}

// Round 15
// 36.662 us; speedup vs baseline: 1.2722x; 1.2722x over previous
//
#include <hip/hip_runtime.h>
#include <math.h>

#define NC 17
#define PLANE 640000              // 200*200*16 voxels per batch
#define H2 (PLANE / 2)            // 320000 float2 per channel-plane
#define J 5                       // float2 slabs per thread
#define TPB 512                   // threads per block
#define BPB 125                   // blocks per batch: 125*512*5 = 320000 float2
#define NBLK1 (2 * BPB)           // 250 blocks
#define PCOLS 256                 // padded row length in part[] (floats)
#define BETA_C 0.95f
#define ALPHA_C 5.0f
#define WPC_C 3.0f
#define IGNORE_C 255

// ---------------------------------------------------------------------------
// Wave64 sum on the VALU pipe via DPP (no DS-pipe bpermute).
// ---------------------------------------------------------------------------
#define DPP_ADD(v, ctrl)                                                        \
    do {                                                                        \
        int _t = __builtin_amdgcn_update_dpp(0, __float_as_int(v), (ctrl),      \
                                             0xf, 0xf, true);                   \
        (v) += __int_as_float(_t);                                              \
    } while (0)

__device__ __forceinline__ float wave_sum_dpp(float v) {
    DPP_ADD(v, 0x111);   // row_shr:1
    DPP_ADD(v, 0x112);   // row_shr:2
    DPP_ADD(v, 0x114);   // row_shr:4
    DPP_ADD(v, 0x118);   // row_shr:8
    DPP_ADD(v, 0x142);   // row_bcast:15
    DPP_ADD(v, 0x143);   // row_bcast:31
    return v;            // full wave sum in lane 63
}

// ws layout: part[51][PCOLS] floats, then acc[51].
// row r = kind*17+c; kind 0=nom, 1=sum_p, 2=cnt

// ---------------------------------------------------------------------------
// K1: softmax + per-class block partials. 10 voxels/thread (5 float2 slabs),
// 2-stage rolling register pipeline (R13 body), 512-thread blocks.
// ---------------------------------------------------------------------------
__global__ __launch_bounds__(TPB) void al_reduce1(const float* __restrict__ pred,
                                                  const int* __restrict__ tgt,
                                                  float* __restrict__ part) {
    const int bb  = blockIdx.x;
    const int b   = (bb >= BPB) ? 1 : 0;                       // block-uniform
    const int base = (bb - b * BPB) * (TPB * J);               // first float2 of block
    const int tid = (int)threadIdx.x;
    const float2* p0 = reinterpret_cast<const float2*>(pred) + (size_t)(b * NC) * H2;
    const int2*   tg = reinterpret_cast<const int2*>(tgt) + (size_t)b * H2;

    __shared__ float lds[3 * NC];
    if (tid < 3 * NC) lds[tid] = 0.f;

    float sump[NC];
#pragma unroll
    for (int c = 0; c < NC; ++c) sump[c] = 0.f;

    float2 xA[NC], xB[NC];
    int2 tA, tB;

#define LOAD_SLAB(X, T, s)                                                      \
    do {                                                                        \
        const int n2 = base + (s) * TPB + tid;                                  \
        _Pragma("unroll")                                                       \
        for (int c = 0; c < NC; ++c) X[c] = p0[(size_t)c * H2 + n2];            \
        T = tg[n2];                                                             \
    } while (0)

#define COMP_SLAB(X, T)                                                         \
    do {                                                                        \
        float2 ss = make_float2(0.f, 0.f);                                      \
        _Pragma("unroll")                                                       \
        for (int c = 0; c < NC; ++c) {                                          \
            X[c].x = __expf(X[c].x); ss.x += X[c].x;                            \
            X[c].y = __expf(X[c].y); ss.y += X[c].y;                            \
        }                                                                       \
        const float j0 = (T.x != IGNORE_C) ? __builtin_amdgcn_rcpf(ss.x) : 0.f; \
        const float j1 = (T.y != IGNORE_C) ? __builtin_amdgcn_rcpf(ss.y) : 0.f; \
        float e0 = 0.f, e1 = 0.f;                                               \
        _Pragma("unroll")                                                       \
        for (int c = 0; c < NC; ++c) {                                          \
            sump[c] += X[c].x * j0 + X[c].y * j1;                               \
            e0 = (c == T.x) ? X[c].x : e0;                                      \
            e1 = (c == T.y) ? X[c].y : e1;                                      \
        }                                                                       \
        if (T.x != IGNORE_C) { atomicAdd(&lds[T.x], e0 * j0);                   \
                               atomicAdd(&lds[2 * NC + T.x], 1.0f); }           \
        if (T.y != IGNORE_C) { atomicAdd(&lds[T.y], e1 * j1);                   \
                               atomicAdd(&lds[2 * NC + T.y], 1.0f); }           \
    } while (0)

    LOAD_SLAB(xA, tA, 0);        // slab 0 in flight
    LOAD_SLAB(xB, tB, 1);        // slab 1 in flight
    __syncthreads();             // lds zero-init visible (loads already issued)

    COMP_SLAB(xA, tA);           // compute 0 while 1 returns
    LOAD_SLAB(xA, tA, 2);
    COMP_SLAB(xB, tB);           // compute 1 while 2 returns
    LOAD_SLAB(xB, tB, 3);
    COMP_SLAB(xA, tA);           // compute 2 while 3 returns
    LOAD_SLAB(xA, tA, 4);
    COMP_SLAB(xB, tB);           // compute 3 while 4 returns
    COMP_SLAB(xA, tA);           // compute 4

#undef LOAD_SLAB
#undef COMP_SLAB

    // single tail: 17 DPP chains; lane 63 of each wave -> LDS
#pragma unroll
    for (int c = 0; c < NC; ++c) sump[c] = wave_sum_dpp(sump[c]);
    if ((tid & 63) == 63) {
#pragma unroll
        for (int c = 0; c < NC; ++c) atomicAdd(&lds[NC + c], sump[c]);
    }
    __syncthreads();

    if (tid < 3 * NC)
        part[(size_t)tid * PCOLS + bb] = lds[tid];
}

// ---------------------------------------------------------------------------
// K2: 51 blocks x 256 threads; each block sums one contiguous 250-col row.
// ---------------------------------------------------------------------------
__global__ __launch_bounds__(256) void al_reduce2(const float* __restrict__ part,
                                                  float* __restrict__ acc) {
    const int r = blockIdx.x;                 // 0..50
    const int tid = (int)threadIdx.x;
    const float* p = part + (size_t)r * PCOLS;

    float s = (tid < NBLK1) ? p[tid] : 0.f;
    s = wave_sum_dpp(s);

    __shared__ float w[4];
    if ((tid & 63) == 63) w[tid >> 6] = s;
    __syncthreads();
    if (tid == 0) acc[r] = (w[0] + w[1]) + (w[2] + w[3]);
}

// ---------------------------------------------------------------------------
// K3: O(C) scalar epilogue.
// ---------------------------------------------------------------------------
__device__ __forceinline__ float bce_ones(float x) {
    // F.binary_cross_entropy(x, ones) = min(-log(max(x,1e-38)), 100)
    return fminf(-logf(fmaxf(x, 1e-38f)), 100.0f);
}

__global__ void al_finalize(const float* __restrict__ acc,
                            const float* __restrict__ f1_list,
                            float* __restrict__ out) {
    if (threadIdx.x != 0 || blockIdx.x != 0) return;

    float nom[NC], sump[NC], cnt[NC];
    float n_mask = 0.f;
    for (int c = 0; c < NC; ++c) {
        nom[c]  = acc[c];
        sump[c] = acc[NC + c];
        cnt[c]  = acc[2 * NC + c];
        n_mask += cnt[c];
    }

    float loss_list[NC], newf1[NC];
    float count = 0.f;
    for (int c = 0; c < NC; ++c) {
        const bool has = cnt[c] > 0.f;
        const float prec = (sump[c] > 0.f) ? nom[c] / sump[c] : 0.f;
        const float rec  = has ? nom[c] / cnt[c] : 0.f;
        const float negc = n_mask - cnt[c];
        const float spec_num = (n_mask - sump[c]) - (cnt[c] - nom[c]);
        const float spec = (negc > 0.f) ? spec_num / negc : 0.f;

        float ll = 0.f;
        if (has) {
            ll  = (sump[c] > 0.f) ? bce_ones(prec) : 0.f;
            ll += bce_ones(rec);
            ll += (negc > 0.f) ? bce_ones(spec) : 0.f;
        }
        loss_list[c] = ll;

        const float den = prec + rec;
        const float f1  = (den > 0.f) ? 2.f * prec * rec / den : 0.f;
        const float cur = has ? f1 : 0.f;
        newf1[c] = BETA_C * f1_list[c] + (1.f - BETA_C) * cur;
        count += has ? 1.f : 0.f;
    }

    const float wp = WPC_C * count;

    float mxl = -INFINITY;
    for (int c = 0; c < NC; ++c) {
        const float lg = (loss_list[c] != 0.f) ? ALPHA_C * (1.f - newf1[c]) : -INFINITY;
        mxl = fmaxf(mxl, lg);
    }
    float e[NC];
    float se = 0.f;
    for (int c = 0; c < NC; ++c) {
        const float lg = (loss_list[c] != 0.f) ? ALPHA_C * (1.f - newf1[c]) : -INFINITY;
        e[c] = expf(lg - mxl);    // exp(-inf) = 0 for unselected classes
        se += e[c];
    }

    float total = 0.f;
    for (int c = 0; c < NC; ++c) {
        const float sm = e[c] / se;
        total += loss_list[c] * (1.f + wp * sm);
    }
    out[0] = total / (count * (1.f + WPC_C));
}

// ---------------------------------------------------------------------------
extern "C" void kernel_launch(void* const* d_in, const int* in_sizes, int n_in,
                              void* d_out, int out_size, void* d_ws, size_t ws_size,
                              hipStream_t stream) {
    const float* pred    = (const float*)d_in[0];
    const int*   tgt     = (const int*)d_in[1];
    const float* f1_list = (const float*)d_in[2];
    float* out  = (float*)d_out;
    float* part = (float*)d_ws;                       // 51 * PCOLS floats
    float* acc  = part + (size_t)(3 * NC) * PCOLS;    // 51 floats

    al_reduce1<<<dim3(NBLK1), dim3(TPB), 0, stream>>>(pred, tgt, part);
    al_reduce2<<<dim3(3 * NC), dim3(256), 0, stream>>>(part, acc);
    al_finalize<<<dim3(1), dim3(64), 0, stream>>>(acc, f1_list, out);
}